// Round 1
// baseline (407.237 us; speedup 1.0000x reference)
//
#include <hip/hip_runtime.h>

// SparseCrop: mask = all(10 <= coords[:, :3] < 90); out = (feats * mask, mask)
// Memory-bound. 16 threads per row, one float4 per thread.
// Masked-out rows (~49%) skip the feats load entirely (exec-mask predication
// suppresses the fetch), saving ~125 MB of HBM reads.

__global__ __launch_bounds__(256) void sparse_crop_kernel(
    const int4* __restrict__ coords,     // (N) int4 per row
    const float4* __restrict__ feats,    // (N*16) float4
    float4* __restrict__ out_feats,      // (N*16) float4
    float* __restrict__ out_mask,        // (N) floats (bool as 0.0/1.0)
    int n)
{
    int tid = blockIdx.x * blockDim.x + threadIdx.x;
    int row = tid >> 4;
    int col = tid & 15;
    if (row >= n) return;

    int4 c = coords[row];  // 16B aligned load; .w unused
    // 10 <= x < 90  <=>  (unsigned)(x - 10) < 80
    bool m = ((unsigned)(c.x - 10) < 80u) &
             ((unsigned)(c.y - 10) < 80u) &
             ((unsigned)(c.z - 10) < 80u);

    float4 v = make_float4(0.f, 0.f, 0.f, 0.f);
    if (m) {
        v = feats[(size_t)row * 16 + col];  // predicated: masked rows never fetch
    }
    out_feats[(size_t)row * 16 + col] = v;

    if (col == 0) {
        out_mask[row] = m ? 1.0f : 0.0f;
    }
}

extern "C" void kernel_launch(void* const* d_in, const int* in_sizes, int n_in,
                              void* d_out, int out_size, void* d_ws, size_t ws_size,
                              hipStream_t stream) {
    const int4* coords  = (const int4*)d_in[0];   // (N,4) int32
    const float4* feats = (const float4*)d_in[1]; // (N,64) fp32

    int n = in_sizes[0] / 4;              // N = 1,000,000
    float* out = (float*)d_out;
    float4* out_feats = (float4*)out;               // first N*64 floats
    float* out_mask   = out + (size_t)n * 64;       // next N floats

    int total_threads = n * 16;
    int blocks = (total_threads + 255) / 256;
    sparse_crop_kernel<<<blocks, 256, 0, stream>>>(coords, feats, out_feats, out_mask, n);
}

// Round 3
// 399.831 us; speedup vs baseline: 1.0185x; 1.0185x over previous
//
#include <hip/hip_runtime.h>

// SparseCrop: mask = all(10 <= coords[:, :3] < 90); out = (feats * mask, mask)
// Memory-bound. 16 threads per row, one float4 per thread.
// Masked-out rows (~49%) skip the feats load entirely (exec-mask predication
// suppresses the fetch), saving ~125 MB of HBM reads.
// R3: non-temporal loads/stores via native clang vector type (HIP float4 is a
// struct and rejected by __builtin_nontemporal_*).

typedef float vfloat4 __attribute__((ext_vector_type(4)));

__global__ __launch_bounds__(256) void sparse_crop_kernel(
    const int4* __restrict__ coords,       // (N) int4 per row
    const vfloat4* __restrict__ feats,     // (N*16) float4
    vfloat4* __restrict__ out_feats,       // (N*16) float4
    float* __restrict__ out_mask,          // (N) floats (bool as 0.0/1.0)
    int n)
{
    int tid = blockIdx.x * blockDim.x + threadIdx.x;
    int row = tid >> 4;
    int col = tid & 15;
    if (row >= n) return;

    int4 c = coords[row];  // 16B aligned load; .w unused; one line per 4 rows
    // 10 <= x < 90  <=>  (unsigned)(x - 10) < 80
    bool m = ((unsigned)(c.x - 10) < 80u) &
             ((unsigned)(c.y - 10) < 80u) &
             ((unsigned)(c.z - 10) < 80u);

    vfloat4 v = (vfloat4)(0.f);
    if (m) {
        // predicated: masked rows never fetch; nt: streamed once, don't cache
        v = __builtin_nontemporal_load(&feats[(size_t)row * 16 + col]);
    }
    __builtin_nontemporal_store(v, &out_feats[(size_t)row * 16 + col]);

    if (col == 0) {
        __builtin_nontemporal_store(m ? 1.0f : 0.0f, &out_mask[row]);
    }
}

extern "C" void kernel_launch(void* const* d_in, const int* in_sizes, int n_in,
                              void* d_out, int out_size, void* d_ws, size_t ws_size,
                              hipStream_t stream) {
    const int4* coords   = (const int4*)d_in[0];    // (N,4) int32
    const vfloat4* feats = (const vfloat4*)d_in[1]; // (N,64) fp32

    int n = in_sizes[0] / 4;              // N = 1,000,000
    float* out = (float*)d_out;
    vfloat4* out_feats = (vfloat4*)out;             // first N*64 floats
    float* out_mask    = out + (size_t)n * 64;      // next N floats

    int total_threads = n * 16;
    int blocks = (total_threads + 255) / 256;
    sparse_crop_kernel<<<blocks, 256, 0, stream>>>(coords, feats, out_feats, out_mask, n);
}